// Round 1
// baseline (80.904 us; speedup 1.0000x reference)
//
#include <hip/hip_runtime.h>

// WeightedSmoothLoss: fused log-softmax + weighted NLL + label smoothing +
// argmax penalty, mean-reduced. logits [B,128] f32, targets [B] int,
// weight [128] f32, penalty_mat [128,128] f32 -> scalar f32.

constexpr int C = 128;
constexpr float SMOOTHING = 0.1f;
constexpr int BLOCK = 256;
constexpr int GRID = 2048;
constexpr int HWPB = BLOCK / 32;  // half-waves (rows) per block per iter = 8

__global__ __launch_bounds__(BLOCK, 2) void wsl_main(
    const float* __restrict__ logits,
    const int* __restrict__ targets,
    const float* __restrict__ weight,
    const float* __restrict__ penalty,
    double* __restrict__ partials,
    int B) {
  const int tid = threadIdx.x;
  const int lane32 = tid & 31;           // lane within half-wave
  const int hw = blockIdx.x * HWPB + (tid >> 5);
  const int nhw = GRID * HWPB;           // total half-waves

  double acc = 0.0;

  for (int row = hw; row < B; row += nhw) {
    const float4 v =
        *reinterpret_cast<const float4*>(logits + (size_t)row * C + lane32 * 4);

    // --- max + argmax (first-occurrence tie-break) ---
    float bv = v.x; int bi = lane32 * 4;
    if (v.y > bv) { bv = v.y; bi = lane32 * 4 + 1; }
    if (v.z > bv) { bv = v.z; bi = lane32 * 4 + 2; }
    if (v.w > bv) { bv = v.w; bi = lane32 * 4 + 3; }
#pragma unroll
    for (int m = 16; m >= 1; m >>= 1) {
      float ov = __shfl_xor(bv, m, 64);
      int   oi = __shfl_xor(bi, m, 64);
      if (ov > bv || (ov == bv && oi < bi)) { bv = ov; bi = oi; }
    }
    // all 32 lanes of this half-wave now hold (row max bv, argmax bi)

    // --- sum(exp(x - max)) and sum(x) ---
    float se = __expf(v.x - bv) + __expf(v.y - bv) +
               __expf(v.z - bv) + __expf(v.w - bv);
    float sl = v.x + v.y + v.z + v.w;
#pragma unroll
    for (int m = 16; m >= 1; m >>= 1) {
      se += __shfl_xor(se, m, 64);
      sl += __shfl_xor(sl, m, 64);
    }
    const float lse = bv + logf(se);

    const int t = targets[row];
    // picked logit: element t lives in lane (t>>2) of this half, slot t&3
    const int sub = t & 3;
    const float sel = (sub == 0) ? v.x : (sub == 1) ? v.y
                    : (sub == 2) ? v.z : v.w;
    const int src_lane = ((tid & 63) & 32) | (t >> 2);  // lane within wave
    const float picked = __shfl(sel, src_lane, 64);

    if (lane32 == 0) {
      const float nll = -(picked - lse) * weight[t];
      const float smooth = lse - sl * (1.0f / C);   // -mean(log_p)
      const float loss = (1.0f - SMOOTHING) * nll + SMOOTHING * smooth;
      const float mask = penalty[t * C + bi];
      acc += (double)(loss * mask);
    }
  }

  // --- block reduction of per-thread partials ---
  __shared__ double sacc[BLOCK];
  sacc[tid] = acc;
  __syncthreads();
#pragma unroll
  for (int s = BLOCK / 2; s > 0; s >>= 1) {
    if (tid < s) sacc[tid] += sacc[tid + s];
    __syncthreads();
  }
  if (tid == 0) partials[blockIdx.x] = sacc[0];
}

__global__ void wsl_reduce(const double* __restrict__ partials,
                           float* __restrict__ out, int n, double invB) {
  __shared__ double s[256];
  double a = 0.0;
  for (int i = threadIdx.x; i < n; i += 256) a += partials[i];
  s[threadIdx.x] = a;
  __syncthreads();
#pragma unroll
  for (int st = 128; st > 0; st >>= 1) {
    if (threadIdx.x < st) s[threadIdx.x] += s[threadIdx.x + st];
    __syncthreads();
  }
  if (threadIdx.x == 0) out[0] = (float)(s[0] * invB);
}

extern "C" void kernel_launch(void* const* d_in, const int* in_sizes, int n_in,
                              void* d_out, int out_size, void* d_ws, size_t ws_size,
                              hipStream_t stream) {
  const float* logits  = (const float*)d_in[0];
  const int*   targets = (const int*)d_in[1];
  const float* weight  = (const float*)d_in[2];
  const float* penalty = (const float*)d_in[3];
  float* out = (float*)d_out;
  double* partials = (double*)d_ws;

  const int B = in_sizes[1];  // number of rows = #targets

  wsl_main<<<GRID, BLOCK, 0, stream>>>(logits, targets, weight, penalty,
                                       partials, B);
  wsl_reduce<<<1, 256, 0, stream>>>(partials, out, GRID, 1.0 / (double)B);
}